// Round 5
// baseline (581.774 us; speedup 1.0000x reference)
//
#include <hip/hip_runtime.h>

#define N_NODES 100000
#define N_EDGES 1600000
#define NGROUPS 8
#define NODES_PER_GROUP 12500   // N_NODES / NGROUPS
#define SCAN_BLOCKS 25          // 25 * 4096 = 102400 >= N_NODES
#define PERM_BLOCKS 10000       // 1250 edge-slices * 8 groups
#define MM1_BLOCKS 6250         // N_NODES / 16

// clang-native 4-float vector: valid for __builtin_nontemporal_load
typedef float vf4 __attribute__((ext_vector_type(4)));

// ---------------------------------------------------------------------------
// CSR build (rebuilt every launch; ws is re-poisoned between calls).
// ---------------------------------------------------------------------------
__global__ __launch_bounds__(1024) void k_zero(int* __restrict__ cnt) {
    int i = blockIdx.x * 1024 + threadIdx.x;
    if (i < N_NODES) cnt[i] = 0;
}

__global__ __launch_bounds__(256) void k_count(const int* __restrict__ ei,
                                               int* __restrict__ cnt) {
    int e = blockIdx.x * 256 + threadIdx.x;
    if (e < N_EDGES) {
        int dst = __builtin_nontemporal_load(&ei[N_EDGES + e]);
        atomicAdd(&cnt[dst], 1);
    }
}

// Hierarchical scan, stage 1: each block scans a 4096-elem chunk (4/thread),
// writes chunk-local EXCLUSIVE scan to off[] and its chunk total to bsum[].
__global__ __launch_bounds__(1024) void k_scan_local(const int* __restrict__ cnt,
                                                     int* __restrict__ off,
                                                     int* __restrict__ bsum) {
    __shared__ int waveSums[16];
    const int tid  = threadIdx.x;
    const int lane = tid & 63;
    const int wid  = tid >> 6;
    const int base = blockIdx.x * 4096 + tid * 4;
    int v0 = 0, v1 = 0, v2 = 0, v3 = 0;
    const bool inR = (base < N_NODES);          // N_NODES % 4 == 0: all-or-none
    if (inR) { int4 q = *(const int4*)&cnt[base]; v0 = q.x; v1 = q.y; v2 = q.z; v3 = q.w; }
    int s = v0 + v1 + v2 + v3;
    int incl = s;
    #pragma unroll
    for (int d = 1; d < 64; d <<= 1) {
        int n = __shfl_up(incl, d, 64);
        if (lane >= d) incl += n;
    }
    if (lane == 63) waveSums[wid] = incl;
    __syncthreads();
    int waveOff = 0, total = 0;
    #pragma unroll
    for (int w = 0; w < 16; ++w) {
        int ws = waveSums[w];
        waveOff += (w < wid) ? ws : 0;
        total   += ws;
    }
    if (inR) {
        int e0 = waveOff + incl - s;            // chunk-local exclusive
        int4 o = {e0, e0 + v0, e0 + v0 + v1, e0 + v0 + v1 + v2};
        *(int4*)&off[base] = o;
    }
    if (tid == 0) bsum[blockIdx.x] = total;
}

// Stage 2: add chunk base (redundant mini-scan of bsum per block), finalize
// off[] and copy to cnt[] as permute cursors.
__global__ __launch_bounds__(1024) void k_scan_fix(int* __restrict__ off,
                                                   int* __restrict__ cnt,
                                                   const int* __restrict__ bsum) {
    const int b = blockIdx.x;
    int add = 0;
    for (int j = 0; j < b; ++j) add += bsum[j];
    const int base = b * 4096 + threadIdx.x * 4;
    if (base < N_NODES) {
        int4 q = *(int4*)&off[base];
        q.x += add; q.y += add; q.z += add; q.w += add;
        *(int4*)&off[base] = q;
        *(int4*)&cnt[base] = q;
    }
    if (b == 0 && threadIdx.x == 0) off[N_NODES] = N_EDGES;
}

// ---------------------------------------------------------------------------
// Fused dispatch: blocks [0, PERM_BLOCKS) do the XCD-partitioned permute;
// blocks [PERM_BLOCKS, PERM_BLOCKS+MM1_BLOCKS) do y = x @ W1 (128->64).
// Independent work, different pipes (atomics vs VALU) -> co-scheduled.
// Streaming reads are non-temporal so L2 keeps srcS slices resident.
// ---------------------------------------------------------------------------
__global__ __launch_bounds__(256) void k_permute_mm1(const int* __restrict__ ei,
                                                     int* __restrict__ cursor,
                                                     int* __restrict__ srcS,
                                                     const float* __restrict__ x,
                                                     const float* __restrict__ W1,
                                                     float* __restrict__ y) {
    __shared__ float sx[16 * 132];   // mm1 x-stage (8.4 KB; only LDS in kernel)
    if (blockIdx.x < PERM_BLOCKS) {
        const int g     = blockIdx.x & 7;          // round-robin block->XCD
        const int slice = blockIdx.x >> 3;
        const int lo    = g * NODES_PER_GROUP;
        const int hi    = lo + NODES_PER_GROUP;
        const int e0    = slice * 1280;            // 1250 slices * 1280 = 1.6M
        #pragma unroll
        for (int i = 0; i < 5; ++i) {
            int e   = e0 + i * 256 + threadIdx.x;
            int dst = __builtin_nontemporal_load(&ei[N_EDGES + e]);
            if (dst >= lo && dst < hi) {
                int src = __builtin_nontemporal_load(&ei[e]);
                int pos = atomicAdd(&cursor[dst], 1);
                srcS[pos] = src;
            }
        }
        return;
    }
    // ---- mm1 branch ----
    const int tid  = threadIdx.x;
    const int row0 = (blockIdx.x - PERM_BLOCKS) * 16;
    {
        const vf4* xv = (const vf4*)x;
        #pragma unroll
        for (int t = 0; t < 2; ++t) {
            int i = tid * 4 + t * 1024;
            int r = i >> 7, c = i & 127;
            vf4 v = __builtin_nontemporal_load(&xv[((size_t)(row0 + r) * 128 + c) >> 2]);
            *(vf4*)&sx[r * 132 + c] = v;
        }
    }
    __syncthreads();
    const int r  = tid >> 4;
    const int cw = tid & 15;                       // float4 column index
    const float4* W1v = (const float4*)W1;
    float4 acc = {0.f, 0.f, 0.f, 0.f};
    #pragma unroll 8
    for (int k = 0; k < 128; ++k) {
        float  xvk = sx[r * 132 + k];
        float4 w   = W1v[k * 16 + cw];             // 256B/wave broadcast, L1-hot
        acc.x += xvk * w.x; acc.y += xvk * w.y; acc.z += xvk * w.z; acc.w += xvk * w.w;
    }
    *(float4*)&y[(size_t)(row0 + r) * 64 + cw * 4] = acc;
}

// ---------------------------------------------------------------------------
// Gather-agg + conv1 epilogue: h1[n] = relu( y[n] + sum_{e: dst==n} y[src_e]
//                                            + b1 )
// One wave per node, lane == channel. No atomics.
// ---------------------------------------------------------------------------
__global__ __launch_bounds__(256) void k_gather_h1(const int* __restrict__ off,
                                                   const int* __restrict__ srcS,
                                                   const float* __restrict__ y,
                                                   const float* __restrict__ b1,
                                                   float* __restrict__ h1) {
    const int node = blockIdx.x * 4 + (threadIdx.x >> 6);   // exact: 25000*4
    const int lane = threadIdx.x & 63;
    const int beg = off[node];
    const int end = off[node + 1];
    float acc = y[(size_t)node * 64 + lane];
    int i = beg;
    for (; i + 4 <= end; i += 4) {
        int s0 = __builtin_nontemporal_load(&srcS[i]);
        int s1 = __builtin_nontemporal_load(&srcS[i + 1]);
        int s2 = __builtin_nontemporal_load(&srcS[i + 2]);
        int s3 = __builtin_nontemporal_load(&srcS[i + 3]);
        float v0 = y[(size_t)s0 * 64 + lane];
        float v1 = y[(size_t)s1 * 64 + lane];
        float v2 = y[(size_t)s2 * 64 + lane];
        float v3 = y[(size_t)s3 * 64 + lane];
        acc += (v0 + v1) + (v2 + v3);
    }
    for (; i < end; ++i) acc += y[(size_t)srcS[i] * 64 + lane];
    h1[(size_t)node * 64 + lane] = fmaxf(acc + b1[lane], 0.f);
}

// ---------------------------------------------------------------------------
// y2 = h1 @ W2 (64x64). W2 read per-k from global (L1-hot broadcast).
// ---------------------------------------------------------------------------
__global__ __launch_bounds__(256) void k_mm2(const float* __restrict__ h1,
                                             const float* __restrict__ W2,
                                             float* __restrict__ y2) {
    __shared__ float sh[16 * 68];
    const int tid = threadIdx.x;
    const int row0 = blockIdx.x * 16;
    {
        int i = tid * 4;                    // exactly 16*64 floats
        int r = i >> 6, c = i & 63;
        vf4 v = __builtin_nontemporal_load(
            (const vf4*)&h1[(size_t)(row0 + r) * 64 + c]);
        *(vf4*)&sh[r * 68 + c] = v;
    }
    __syncthreads();
    const int r  = tid >> 4;
    const int cw = tid & 15;
    const float4* W2v = (const float4*)W2;
    float4 acc = {0.f, 0.f, 0.f, 0.f};
    #pragma unroll 8
    for (int k = 0; k < 64; ++k) {
        float  hv = sh[r * 68 + k];
        float4 w  = W2v[k * 16 + cw];
        acc.x += hv * w.x; acc.y += hv * w.y; acc.z += hv * w.z; acc.w += hv * w.w;
    }
    *(float4*)&y2[(size_t)(row0 + r) * 64 + cw * 4] = acc;
}

// ---------------------------------------------------------------------------
// Gather-agg + full tail: z2 = y2[n] + sum y2[src]; h2 = relu(z2+b2);
// h3 = relu(h2@W3+b3); out = h3@W4+b4.  LDS row round-trip + shfl reduce.
// ---------------------------------------------------------------------------
__global__ __launch_bounds__(256) void k_gather_tail(const int* __restrict__ off,
                                                     const int* __restrict__ srcS,
                                                     const float* __restrict__ y2,
                                                     const float* __restrict__ b2,
                                                     const float* __restrict__ W3,
                                                     const float* __restrict__ b3,
                                                     const float* __restrict__ W4,
                                                     const float* __restrict__ b4,
                                                     float* __restrict__ out) {
    __shared__ float sh[4 * 64];
    const int wid  = threadIdx.x >> 6;
    const int lane = threadIdx.x & 63;
    const int node = blockIdx.x * 4 + wid;                  // exact
    const int beg = off[node];
    const int end = off[node + 1];
    float acc = y2[(size_t)node * 64 + lane];
    int i = beg;
    for (; i + 4 <= end; i += 4) {
        int s0 = __builtin_nontemporal_load(&srcS[i]);
        int s1 = __builtin_nontemporal_load(&srcS[i + 1]);
        int s2 = __builtin_nontemporal_load(&srcS[i + 2]);
        int s3 = __builtin_nontemporal_load(&srcS[i + 3]);
        float v0 = y2[(size_t)s0 * 64 + lane];
        float v1 = y2[(size_t)s1 * 64 + lane];
        float v2 = y2[(size_t)s2 * 64 + lane];
        float v3 = y2[(size_t)s3 * 64 + lane];
        acc += (v0 + v1) + (v2 + v3);
    }
    for (; i < end; ++i) acc += y2[(size_t)srcS[i] * 64 + lane];

    sh[wid * 64 + lane] = fmaxf(acc + b2[lane], 0.f);       // h2 row
    __syncthreads();                                        // uniform: exact grid
    float u = 0.f;
    if (lane < 16) {
        float t = b3[lane];
        #pragma unroll 16
        for (int k = 0; k < 64; ++k)
            t += sh[wid * 64 + k] * W3[k * 16 + lane];      // 64B/16-lane, L1-hot
        u = fmaxf(t, 0.f) * W4[lane];
    }
    #pragma unroll
    for (int s = 8; s; s >>= 1) u += __shfl_down(u, s, 64);
    if (lane == 0) out[node] = u + b4[0];
}

extern "C" void kernel_launch(void* const* d_in, const int* in_sizes, int n_in,
                              void* d_out, int out_size, void* d_ws, size_t ws_size,
                              hipStream_t stream) {
    const float* x  = (const float*)d_in[0];
    const int*   ei = (const int*)d_in[1];
    const float* W1 = (const float*)d_in[2];
    const float* b1 = (const float*)d_in[3];
    const float* W2 = (const float*)d_in[4];
    const float* b2 = (const float*)d_in[5];
    const float* W3 = (const float*)d_in[6];
    const float* b3 = (const float*)d_in[7];
    const float* W4 = (const float*)d_in[8];
    const float* b4 = (const float*)d_in[9];
    float* out = (float*)d_out;

    // ws layout: y | z | cnt/cursor | off | srcSorted | bsum
    float* bufA = (float*)d_ws;
    float* bufB = bufA + (size_t)N_NODES * 64;
    int*   cnt  = (int*)(bufB + (size_t)N_NODES * 64);
    int*   off  = cnt + N_NODES;
    int*   srcS = off + N_NODES + 4;
    int*   bsum = srcS + N_EDGES;

    const int edgeBlocks = (N_EDGES + 255) / 256;     // 6250
    const int mmBlocks   = N_NODES / 16;              // 6250
    const int aggBlocks  = N_NODES / 4;               // 25000 (exact)

    k_zero<<<(N_NODES + 1023) / 1024, 1024, 0, stream>>>(cnt);
    k_count<<<edgeBlocks, 256, 0, stream>>>(ei, cnt);
    k_scan_local<<<SCAN_BLOCKS, 1024, 0, stream>>>(cnt, off, bsum);
    k_scan_fix<<<SCAN_BLOCKS, 1024, 0, stream>>>(off, cnt, bsum);
    // permute + mm1 co-scheduled in one dispatch
    k_permute_mm1<<<PERM_BLOCKS + MM1_BLOCKS, 256, 0, stream>>>(ei, cnt, srcS,
                                                                x, W1, bufA);
    // conv1 agg + bias + relu
    k_gather_h1<<<aggBlocks, 256, 0, stream>>>(off, srcS, bufA, b1, bufB);
    // conv2 matmul
    k_mm2<<<mmBlocks, 256, 0, stream>>>(bufB, W2, bufA);
    // conv2 agg + full MLP tail
    k_gather_tail<<<aggBlocks, 256, 0, stream>>>(off, srcS, bufA, b2, W3, b3,
                                                 W4, b4, out);
}

// Round 6
// 489.109 us; speedup vs baseline: 1.1895x; 1.1895x over previous
//
#include <hip/hip_runtime.h>

#define N_NODES 100000
#define N_EDGES 1600000
#define NGROUPS 8
#define NODES_PER_GROUP 12500   // N_NODES / NGROUPS
#define SCAN_BLOCKS 25          // 25 * 4096 = 102400 >= N_NODES

// bf16 helpers (round-to-nearest-even encode, shift decode)
__device__ __forceinline__ unsigned short bf16enc(float f) {
    unsigned int u = __float_as_uint(f);
    return (unsigned short)((u + 0x7FFFu + ((u >> 16) & 1u)) >> 16);
}
__device__ __forceinline__ float bf16dec(unsigned short h) {
    return __uint_as_float((unsigned int)h << 16);
}

// ---------------------------------------------------------------------------
// CSR build (rebuilt every launch; ws is re-poisoned between calls).
// ---------------------------------------------------------------------------
__global__ __launch_bounds__(1024) void k_zero(int* __restrict__ cnt) {
    int i = blockIdx.x * 1024 + threadIdx.x;
    if (i < N_NODES) cnt[i] = 0;
}

__global__ __launch_bounds__(256) void k_count(const int* __restrict__ ei,
                                               int* __restrict__ cnt) {
    int e = blockIdx.x * 256 + threadIdx.x;
    if (e < N_EDGES) atomicAdd(&cnt[ei[N_EDGES + e]], 1);
}

// Hierarchical scan, stage 1: block-local exclusive scan of 4096-elem chunks.
__global__ __launch_bounds__(1024) void k_scan_local(const int* __restrict__ cnt,
                                                     int* __restrict__ off,
                                                     int* __restrict__ bsum) {
    __shared__ int waveSums[16];
    const int tid  = threadIdx.x;
    const int lane = tid & 63;
    const int wid  = tid >> 6;
    const int base = blockIdx.x * 4096 + tid * 4;
    int v0 = 0, v1 = 0, v2 = 0, v3 = 0;
    const bool inR = (base < N_NODES);          // N_NODES % 4 == 0: all-or-none
    if (inR) { int4 q = *(const int4*)&cnt[base]; v0 = q.x; v1 = q.y; v2 = q.z; v3 = q.w; }
    int s = v0 + v1 + v2 + v3;
    int incl = s;
    #pragma unroll
    for (int d = 1; d < 64; d <<= 1) {
        int n = __shfl_up(incl, d, 64);
        if (lane >= d) incl += n;
    }
    if (lane == 63) waveSums[wid] = incl;
    __syncthreads();
    int waveOff = 0, total = 0;
    #pragma unroll
    for (int w = 0; w < 16; ++w) {
        int ws = waveSums[w];
        waveOff += (w < wid) ? ws : 0;
        total   += ws;
    }
    if (inR) {
        int e0 = waveOff + incl - s;            // chunk-local exclusive
        int4 o = {e0, e0 + v0, e0 + v0 + v1, e0 + v0 + v1 + v2};
        *(int4*)&off[base] = o;
    }
    if (tid == 0) bsum[blockIdx.x] = total;
}

// Stage 2: add chunk base, finalize off[] and copy to cnt[] as cursors.
__global__ __launch_bounds__(1024) void k_scan_fix(int* __restrict__ off,
                                                   int* __restrict__ cnt,
                                                   const int* __restrict__ bsum) {
    const int b = blockIdx.x;
    int add = 0;
    for (int j = 0; j < b; ++j) add += bsum[j];
    const int base = b * 4096 + threadIdx.x * 4;
    if (base < N_NODES) {
        int4 q = *(int4*)&off[base];
        q.x += add; q.y += add; q.z += add; q.w += add;
        *(int4*)&off[base] = q;
        *(int4*)&cnt[base] = q;
    }
    if (b == 0 && threadIdx.x == 0) off[N_NODES] = N_EDGES;
}

// XCD-partitioned permute (R3-proven form: plain loads, no NT).
__global__ __launch_bounds__(256) void k_permute(const int* __restrict__ ei,
                                                 int* __restrict__ cursor,
                                                 int* __restrict__ srcS) {
    const int g     = blockIdx.x & 7;
    const int slice = blockIdx.x >> 3;
    const int lo    = g * NODES_PER_GROUP;
    const int hi    = lo + NODES_PER_GROUP;
    const int e0    = slice * 1280;             // 1250 slices * 1280 = 1.6M exact
    #pragma unroll
    for (int i = 0; i < 5; ++i) {
        int e   = e0 + i * 256 + threadIdx.x;
        int dst = ei[N_EDGES + e];
        if (dst >= lo && dst < hi) {
            int src = ei[e];
            int pos = atomicAdd(&cursor[dst], 1);
            srcS[pos] = src;
        }
    }
}

// ---------------------------------------------------------------------------
// K1: y = x @ W1 (N x 128 @ 128 x 64), output stored bf16 (gather payload).
// ---------------------------------------------------------------------------
__global__ __launch_bounds__(256) void k_mm1(const float* __restrict__ x,
                                             const float* __restrict__ W1,
                                             unsigned short* __restrict__ yb) {
    __shared__ float sW[128 * 64];   // 32 KB
    __shared__ float sx[16 * 132];
    const int tid = threadIdx.x;
    for (int i = tid * 4; i < 128 * 64; i += 1024)
        *(float4*)&sW[i] = *(const float4*)&W1[i];
    const int row0 = blockIdx.x * 16;
    for (int i = tid * 4; i < 16 * 128; i += 1024) {
        int r = i >> 7, c = i & 127;
        *(float4*)&sx[r * 132 + c] = *(const float4*)&x[(size_t)(row0 + r) * 128 + c];
    }
    __syncthreads();
    const int r  = tid >> 4;
    const int c4 = (tid & 15) * 4;
    float4 acc = {0.f, 0.f, 0.f, 0.f};
    #pragma unroll 16
    for (int k = 0; k < 128; ++k) {
        float  xv = sx[r * 132 + k];
        float4 w  = *(float4*)&sW[k * 64 + c4];
        acc.x += xv * w.x; acc.y += xv * w.y; acc.z += xv * w.z; acc.w += xv * w.w;
    }
    ushort4 o = {bf16enc(acc.x), bf16enc(acc.y), bf16enc(acc.z), bf16enc(acc.w)};
    *(ushort4*)&yb[(size_t)(row0 + r) * 64 + c4] = o;
}

// ---------------------------------------------------------------------------
// Gather-agg + conv1 epilogue: h1[n] = relu( y[n] + sum y[src] + b1 ), fp32
// accumulate over bf16 payload. One wave per node, lane == channel.
// srcS reads are NT (read-once stream) so they don't evict y from L2.
// ---------------------------------------------------------------------------
__global__ __launch_bounds__(256) void k_gather_h1(const int* __restrict__ off,
                                                   const int* __restrict__ srcS,
                                                   const unsigned short* __restrict__ yb,
                                                   const float* __restrict__ b1,
                                                   float* __restrict__ h1) {
    const int node = blockIdx.x * 4 + (threadIdx.x >> 6);   // exact: 25000*4
    const int lane = threadIdx.x & 63;
    const int beg = off[node];
    const int end = off[node + 1];
    float acc = bf16dec(yb[(size_t)node * 64 + lane]);
    int i = beg;
    for (; i + 4 <= end; i += 4) {
        int s0 = __builtin_nontemporal_load(&srcS[i]);
        int s1 = __builtin_nontemporal_load(&srcS[i + 1]);
        int s2 = __builtin_nontemporal_load(&srcS[i + 2]);
        int s3 = __builtin_nontemporal_load(&srcS[i + 3]);
        float v0 = bf16dec(yb[(size_t)s0 * 64 + lane]);
        float v1 = bf16dec(yb[(size_t)s1 * 64 + lane]);
        float v2 = bf16dec(yb[(size_t)s2 * 64 + lane]);
        float v3 = bf16dec(yb[(size_t)s3 * 64 + lane]);
        acc += (v0 + v1) + (v2 + v3);
    }
    for (; i < end; ++i) acc += bf16dec(yb[(size_t)srcS[i] * 64 + lane]);
    h1[(size_t)node * 64 + lane] = fmaxf(acc + b1[lane], 0.f);
}

// ---------------------------------------------------------------------------
// y2 = h1 @ W2 (64x64), output stored bf16.
// ---------------------------------------------------------------------------
__global__ __launch_bounds__(256) void k_mm2(const float* __restrict__ h1,
                                             const float* __restrict__ W2,
                                             unsigned short* __restrict__ y2b) {
    __shared__ float sW[64 * 64];    // 16 KB
    __shared__ float sh[16 * 68];
    const int tid = threadIdx.x;
    for (int i = tid * 4; i < 64 * 64; i += 1024)
        *(float4*)&sW[i] = *(const float4*)&W2[i];
    const int row0 = blockIdx.x * 16;
    {
        int i = tid * 4;             // exactly 16*64 floats
        int r = i >> 6, c = i & 63;
        *(float4*)&sh[r * 68 + c] = *(const float4*)&h1[(size_t)(row0 + r) * 64 + c];
    }
    __syncthreads();
    const int r  = tid >> 4;
    const int c4 = (tid & 15) * 4;
    float4 acc = {0.f, 0.f, 0.f, 0.f};
    #pragma unroll 16
    for (int k = 0; k < 64; ++k) {
        float  hv = sh[r * 68 + k];
        float4 w  = *(float4*)&sW[k * 64 + c4];
        acc.x += hv * w.x; acc.y += hv * w.y; acc.z += hv * w.z; acc.w += hv * w.w;
    }
    ushort4 o = {bf16enc(acc.x), bf16enc(acc.y), bf16enc(acc.z), bf16enc(acc.w)};
    *(ushort4*)&y2b[(size_t)(row0 + r) * 64 + c4] = o;
}

// ---------------------------------------------------------------------------
// Gather-agg + full tail: z2 = y2[n] + sum y2[src]; h2 = relu(z2+b2);
// h3 = relu(h2@W3+b3); out = h3@W4+b4.  LDS row round-trip + shfl reduce.
// ---------------------------------------------------------------------------
__global__ __launch_bounds__(256) void k_gather_tail(const int* __restrict__ off,
                                                     const int* __restrict__ srcS,
                                                     const unsigned short* __restrict__ y2b,
                                                     const float* __restrict__ b2,
                                                     const float* __restrict__ W3,
                                                     const float* __restrict__ b3,
                                                     const float* __restrict__ W4,
                                                     const float* __restrict__ b4,
                                                     float* __restrict__ out) {
    __shared__ float sh[4 * 64];
    const int wid  = threadIdx.x >> 6;
    const int lane = threadIdx.x & 63;
    const int node = blockIdx.x * 4 + wid;                  // exact
    const int beg = off[node];
    const int end = off[node + 1];
    float acc = bf16dec(y2b[(size_t)node * 64 + lane]);
    int i = beg;
    for (; i + 4 <= end; i += 4) {
        int s0 = __builtin_nontemporal_load(&srcS[i]);
        int s1 = __builtin_nontemporal_load(&srcS[i + 1]);
        int s2 = __builtin_nontemporal_load(&srcS[i + 2]);
        int s3 = __builtin_nontemporal_load(&srcS[i + 3]);
        float v0 = bf16dec(y2b[(size_t)s0 * 64 + lane]);
        float v1 = bf16dec(y2b[(size_t)s1 * 64 + lane]);
        float v2 = bf16dec(y2b[(size_t)s2 * 64 + lane]);
        float v3 = bf16dec(y2b[(size_t)s3 * 64 + lane]);
        acc += (v0 + v1) + (v2 + v3);
    }
    for (; i < end; ++i) acc += bf16dec(y2b[(size_t)srcS[i] * 64 + lane]);

    sh[wid * 64 + lane] = fmaxf(acc + b2[lane], 0.f);       // h2 row
    __syncthreads();                                        // uniform: exact grid
    float u = 0.f;
    if (lane < 16) {
        float t = b3[lane];
        #pragma unroll 16
        for (int k = 0; k < 64; ++k)
            t += sh[wid * 64 + k] * W3[k * 16 + lane];      // L1-hot broadcast
        u = fmaxf(t, 0.f) * W4[lane];
    }
    #pragma unroll
    for (int s = 8; s; s >>= 1) u += __shfl_down(u, s, 64);
    if (lane == 0) out[node] = u + b4[0];
}

extern "C" void kernel_launch(void* const* d_in, const int* in_sizes, int n_in,
                              void* d_out, int out_size, void* d_ws, size_t ws_size,
                              hipStream_t stream) {
    const float* x  = (const float*)d_in[0];
    const int*   ei = (const int*)d_in[1];
    const float* W1 = (const float*)d_in[2];
    const float* b1 = (const float*)d_in[3];
    const float* W2 = (const float*)d_in[4];
    const float* b2 = (const float*)d_in[5];
    const float* W3 = (const float*)d_in[6];
    const float* b3 = (const float*)d_in[7];
    const float* W4 = (const float*)d_in[8];
    const float* b4 = (const float*)d_in[9];
    float* out = (float*)d_out;

    // ws layout: yb (bf16, reused as y2b) | h1 (fp32) | cnt | off | srcS | bsum
    unsigned short* yb = (unsigned short*)d_ws;                    // 12.8 MB
    float* h1   = (float*)(yb + (size_t)N_NODES * 64);             // 25.6 MB
    int*   cnt  = (int*)(h1 + (size_t)N_NODES * 64);
    int*   off  = cnt + N_NODES;
    int*   srcS = off + N_NODES + 4;
    int*   bsum = srcS + N_EDGES;

    const int edgeBlocks = (N_EDGES + 255) / 256;     // 6250
    const int permBlocks = 1250 * NGROUPS;            // 10000
    const int mmBlocks   = N_NODES / 16;              // 6250
    const int aggBlocks  = N_NODES / 4;               // 25000 (exact)

    // CSR build (once per launch, used by both convs)
    k_zero<<<(N_NODES + 1023) / 1024, 1024, 0, stream>>>(cnt);
    k_count<<<edgeBlocks, 256, 0, stream>>>(ei, cnt);
    k_scan_local<<<SCAN_BLOCKS, 1024, 0, stream>>>(cnt, off, bsum);
    k_scan_fix<<<SCAN_BLOCKS, 1024, 0, stream>>>(off, cnt, bsum);
    k_permute<<<permBlocks, 256, 0, stream>>>(ei, cnt, srcS);

    // conv1: y1 = x@W1 (bf16) ; h1 = relu(y1 + gather(y1) + b1)
    k_mm1<<<mmBlocks, 256, 0, stream>>>(x, W1, yb);
    k_gather_h1<<<aggBlocks, 256, 0, stream>>>(off, srcS, yb, b1, h1);
    // conv2: y2 = h1@W2 (bf16, reuses yb) ; out = tail(y2 + gather(y2))
    k_mm2<<<mmBlocks, 256, 0, stream>>>(h1, W2, yb);
    k_gather_tail<<<aggBlocks, 256, 0, stream>>>(off, srcS, yb, b2, W3, b3,
                                                 W4, b4, out);
}

// Round 7
// 471.178 us; speedup vs baseline: 1.2347x; 1.0381x over previous
//
#include <hip/hip_runtime.h>

#define N_NODES 100000
#define N_EDGES 1600000
#define NGROUPS 8
#define NODES_PER_GROUP 12500   // N_NODES / NGROUPS
#define SCAN_BLOCKS 25          // 25 * 4096 = 102400 >= N_NODES

// bf16 helpers
__device__ __forceinline__ unsigned short bf16enc(float f) {
    unsigned int u = __float_as_uint(f);
    return (unsigned short)((u + 0x7FFFu + ((u >> 16) & 1u)) >> 16);
}
__device__ __forceinline__ float declo(unsigned int u) {   // even channel
    return __uint_as_float(u << 16);
}
__device__ __forceinline__ float dechi(unsigned int u) {   // odd channel
    return __uint_as_float(u & 0xFFFF0000u);
}

// ---------------------------------------------------------------------------
// CSR build (rebuilt every launch).
// ---------------------------------------------------------------------------
__global__ __launch_bounds__(256) void k_count(const int* __restrict__ ei,
                                               int* __restrict__ cnt) {
    int e = blockIdx.x * 256 + threadIdx.x;
    if (e < N_EDGES) atomicAdd(&cnt[ei[N_EDGES + e]], 1);
}

__global__ __launch_bounds__(1024) void k_scan_local(const int* __restrict__ cnt,
                                                     int* __restrict__ off,
                                                     int* __restrict__ bsum) {
    __shared__ int waveSums[16];
    const int tid  = threadIdx.x;
    const int lane = tid & 63;
    const int wid  = tid >> 6;
    const int base = blockIdx.x * 4096 + tid * 4;
    int v0 = 0, v1 = 0, v2 = 0, v3 = 0;
    const bool inR = (base < N_NODES);
    if (inR) { int4 q = *(const int4*)&cnt[base]; v0 = q.x; v1 = q.y; v2 = q.z; v3 = q.w; }
    int s = v0 + v1 + v2 + v3;
    int incl = s;
    #pragma unroll
    for (int d = 1; d < 64; d <<= 1) {
        int n = __shfl_up(incl, d, 64);
        if (lane >= d) incl += n;
    }
    if (lane == 63) waveSums[wid] = incl;
    __syncthreads();
    int waveOff = 0, total = 0;
    #pragma unroll
    for (int w = 0; w < 16; ++w) {
        int ws = waveSums[w];
        waveOff += (w < wid) ? ws : 0;
        total   += ws;
    }
    if (inR) {
        int e0 = waveOff + incl - s;
        int4 o = {e0, e0 + v0, e0 + v0 + v1, e0 + v0 + v1 + v2};
        *(int4*)&off[base] = o;
    }
    if (tid == 0) bsum[blockIdx.x] = total;
}

__global__ __launch_bounds__(1024) void k_scan_fix(int* __restrict__ off,
                                                   int* __restrict__ cnt,
                                                   const int* __restrict__ bsum) {
    const int b = blockIdx.x;
    int add = 0;
    for (int j = 0; j < b; ++j) add += bsum[j];
    const int base = b * 4096 + threadIdx.x * 4;
    if (base < N_NODES) {
        int4 q = *(int4*)&off[base];
        q.x += add; q.y += add; q.z += add; q.w += add;
        *(int4*)&off[base] = q;
        *(int4*)&cnt[base] = q;
    }
    if (b == 0 && threadIdx.x == 0) off[N_NODES] = N_EDGES;
}

// XCD-partitioned permute (R3-proven: plain loads, no NT).
__global__ __launch_bounds__(256) void k_permute(const int* __restrict__ ei,
                                                 int* __restrict__ cursor,
                                                 int* __restrict__ srcS) {
    const int g     = blockIdx.x & 7;
    const int slice = blockIdx.x >> 3;
    const int lo    = g * NODES_PER_GROUP;
    const int hi    = lo + NODES_PER_GROUP;
    const int e0    = slice * 1280;
    #pragma unroll
    for (int i = 0; i < 5; ++i) {
        int e   = e0 + i * 256 + threadIdx.x;
        int dst = ei[N_EDGES + e];
        if (dst >= lo && dst < hi) {
            int src = ei[e];
            int pos = atomicAdd(&cursor[dst], 1);
            srcS[pos] = src;
        }
    }
}

// ---------------------------------------------------------------------------
// K1: y = x @ W1 (N x 128 @ 128 x 64), output bf16.
// ---------------------------------------------------------------------------
__global__ __launch_bounds__(256) void k_mm1(const float* __restrict__ x,
                                             const float* __restrict__ W1,
                                             unsigned short* __restrict__ yb) {
    __shared__ float sW[128 * 64];
    __shared__ float sx[16 * 132];
    const int tid = threadIdx.x;
    for (int i = tid * 4; i < 128 * 64; i += 1024)
        *(float4*)&sW[i] = *(const float4*)&W1[i];
    const int row0 = blockIdx.x * 16;
    for (int i = tid * 4; i < 16 * 128; i += 1024) {
        int r = i >> 7, c = i & 127;
        *(float4*)&sx[r * 132 + c] = *(const float4*)&x[(size_t)(row0 + r) * 128 + c];
    }
    __syncthreads();
    const int r  = tid >> 4;
    const int c4 = (tid & 15) * 4;
    float4 acc = {0.f, 0.f, 0.f, 0.f};
    #pragma unroll 16
    for (int k = 0; k < 128; ++k) {
        float  xv = sx[r * 132 + k];
        float4 w  = *(float4*)&sW[k * 64 + c4];
        acc.x += xv * w.x; acc.y += xv * w.y; acc.z += xv * w.z; acc.w += xv * w.w;
    }
    ushort4 o = {bf16enc(acc.x), bf16enc(acc.y), bf16enc(acc.z), bf16enc(acc.w)};
    *(ushort4*)&yb[(size_t)(row0 + r) * 64 + c4] = o;
}

// ---------------------------------------------------------------------------
// Gather phase (shared pattern): wave = node; 4 groups of 16 lanes; group g
// handles edges beg+g, beg+g+4, ... Each lane reads uint2 (4 bf16 channels),
// so ONE wave-instruction gathers 4 edge-rows (4x MLP vs lane=channel).
// Butterfly shfl_xor(16,32) combines groups; every lane ends with the full
// sum of its 4 channels (j = lane & 15 -> channels 4j..4j+3).
// ---------------------------------------------------------------------------
__device__ __forceinline__ float4 gather_rows(const int* __restrict__ srcS,
                                              const uint2* __restrict__ yv,
                                              int beg, int end, int grp, int j) {
    float4 acc = {0.f, 0.f, 0.f, 0.f};
    int e = beg + grp;
    for (; e + 4 < end; e += 8) {           // 2 rows in flight per group
        int s0 = __builtin_nontemporal_load(&srcS[e]);
        int s1 = __builtin_nontemporal_load(&srcS[e + 4]);
        uint2 v0 = yv[(size_t)s0 * 16 + j];
        uint2 v1 = yv[(size_t)s1 * 16 + j];
        acc.x += declo(v0.x) + declo(v1.x);
        acc.y += dechi(v0.x) + dechi(v1.x);
        acc.z += declo(v0.y) + declo(v1.y);
        acc.w += dechi(v0.y) + dechi(v1.y);
    }
    if (e < end) {
        int s0 = __builtin_nontemporal_load(&srcS[e]);
        uint2 v0 = yv[(size_t)s0 * 16 + j];
        acc.x += declo(v0.x); acc.y += dechi(v0.x);
        acc.z += declo(v0.y); acc.w += dechi(v0.y);
    }
    // combine the 4 groups (butterfly)
    #pragma unroll
    for (int d = 16; d < 64; d <<= 1) {
        acc.x += __shfl_xor(acc.x, d, 64);
        acc.y += __shfl_xor(acc.y, d, 64);
        acc.z += __shfl_xor(acc.z, d, 64);
        acc.w += __shfl_xor(acc.w, d, 64);
    }
    return acc;
}

// ---------------------------------------------------------------------------
// conv1 agg + relu + mm2 fused: h1 = relu(y1[n] + sum y1[src] + b1) (LDS),
// then y2b[n] = bf16(h1 @ W2).  Wave = node, 4 nodes/block.
// ---------------------------------------------------------------------------
__global__ __launch_bounds__(256) void k_gather_h1_mm2(const int* __restrict__ off,
                                                       const int* __restrict__ srcS,
                                                       const unsigned short* __restrict__ yb,
                                                       const float* __restrict__ b1,
                                                       const float* __restrict__ W2,
                                                       unsigned short* __restrict__ y2b) {
    __shared__ float sh[4 * 64];
    const int wid  = threadIdx.x >> 6;
    const int lane = threadIdx.x & 63;
    const int grp  = lane >> 4;
    const int j    = lane & 15;
    const int node = blockIdx.x * 4 + wid;                  // exact: 25000*4
    const int beg = off[node];
    const int end = off[node + 1];
    const uint2* yv = (const uint2*)yb;
    float4 acc = gather_rows(srcS, yv, beg, end, grp, j);
    if (grp == 0) {                                         // finish channels 4j..4j+3
        uint2 sv  = yv[(size_t)node * 16 + j];              // self term
        float4 bb = *(const float4*)&b1[j * 4];
        float4 h;
        h.x = fmaxf(acc.x + declo(sv.x) + bb.x, 0.f);
        h.y = fmaxf(acc.y + dechi(sv.x) + bb.y, 0.f);
        h.z = fmaxf(acc.z + declo(sv.y) + bb.z, 0.f);
        h.w = fmaxf(acc.w + dechi(sv.y) + bb.w, 0.f);
        *(float4*)&sh[wid * 64 + j * 4] = h;
    }
    __syncthreads();
    // phase 2: y2[node][lane] = sum_k h1[k] * W2[k][lane]   (W2 L1-hot)
    float t = 0.f;
    #pragma unroll 8
    for (int k = 0; k < 64; ++k)
        t += sh[wid * 64 + k] * W2[k * 64 + lane];
    y2b[(size_t)node * 64 + lane] = bf16enc(t);
}

// ---------------------------------------------------------------------------
// conv2 agg + full MLP tail: h2 = relu(z2+b2); h3 = relu(h2@W3+b3);
// out = h3@W4+b4.
// ---------------------------------------------------------------------------
__global__ __launch_bounds__(256) void k_gather_tail(const int* __restrict__ off,
                                                     const int* __restrict__ srcS,
                                                     const unsigned short* __restrict__ y2b,
                                                     const float* __restrict__ b2,
                                                     const float* __restrict__ W3,
                                                     const float* __restrict__ b3,
                                                     const float* __restrict__ W4,
                                                     const float* __restrict__ b4,
                                                     float* __restrict__ out) {
    __shared__ float sh[4 * 64];
    const int wid  = threadIdx.x >> 6;
    const int lane = threadIdx.x & 63;
    const int grp  = lane >> 4;
    const int j    = lane & 15;
    const int node = blockIdx.x * 4 + wid;
    const int beg = off[node];
    const int end = off[node + 1];
    const uint2* yv = (const uint2*)y2b;
    float4 acc = gather_rows(srcS, yv, beg, end, grp, j);
    if (grp == 0) {
        uint2 sv  = yv[(size_t)node * 16 + j];
        float4 bb = *(const float4*)&b2[j * 4];
        float4 h;
        h.x = fmaxf(acc.x + declo(sv.x) + bb.x, 0.f);
        h.y = fmaxf(acc.y + dechi(sv.x) + bb.y, 0.f);
        h.z = fmaxf(acc.z + declo(sv.y) + bb.z, 0.f);
        h.w = fmaxf(acc.w + dechi(sv.y) + bb.w, 0.f);
        *(float4*)&sh[wid * 64 + j * 4] = h;
    }
    __syncthreads();
    float u = 0.f;
    if (lane < 16) {
        float t = b3[lane];
        #pragma unroll 16
        for (int k = 0; k < 64; ++k)
            t += sh[wid * 64 + k] * W3[k * 16 + lane];      // L1-hot broadcast
        u = fmaxf(t, 0.f) * W4[lane];
    }
    #pragma unroll
    for (int s = 8; s; s >>= 1) u += __shfl_down(u, s, 64);
    if (lane == 0) out[node] = u + b4[0];
}

extern "C" void kernel_launch(void* const* d_in, const int* in_sizes, int n_in,
                              void* d_out, int out_size, void* d_ws, size_t ws_size,
                              hipStream_t stream) {
    const float* x  = (const float*)d_in[0];
    const int*   ei = (const int*)d_in[1];
    const float* W1 = (const float*)d_in[2];
    const float* b1 = (const float*)d_in[3];
    const float* W2 = (const float*)d_in[4];
    const float* b2 = (const float*)d_in[5];
    const float* W3 = (const float*)d_in[6];
    const float* b3 = (const float*)d_in[7];
    const float* W4 = (const float*)d_in[8];
    const float* b4 = (const float*)d_in[9];
    float* out = (float*)d_out;

    // ws layout: yb (bf16, reused for y2b) | cnt | off | srcS | bsum  (~20 MB)
    unsigned short* yb = (unsigned short*)d_ws;                    // 12.8 MB
    int*   cnt  = (int*)(yb + (size_t)N_NODES * 64);
    int*   off  = cnt + N_NODES;
    int*   srcS = off + N_NODES + 4;
    int*   bsum = srcS + N_EDGES;

    const int edgeBlocks = (N_EDGES + 255) / 256;     // 6250
    const int permBlocks = 1250 * NGROUPS;            // 10000
    const int mmBlocks   = N_NODES / 16;              // 6250
    const int aggBlocks  = N_NODES / 4;               // 25000 (exact)

    // CSR build
    hipMemsetAsync(cnt, 0, (size_t)N_NODES * sizeof(int), stream);
    k_count<<<edgeBlocks, 256, 0, stream>>>(ei, cnt);
    k_scan_local<<<SCAN_BLOCKS, 1024, 0, stream>>>(cnt, off, bsum);
    k_scan_fix<<<SCAN_BLOCKS, 1024, 0, stream>>>(off, cnt, bsum);
    k_permute<<<permBlocks, 256, 0, stream>>>(ei, cnt, srcS);

    // conv1: y1 = x@W1 (bf16); then fused agg+relu+mm2 -> y2 (bf16, in-place safe:
    // each block writes only its own nodes' rows after reading all needed rows?
    // NOT in-place: y2 written to same yb would race with other blocks' gathers.
    // -> use second half of ws for y2.
    k_mm1<<<mmBlocks, 256, 0, stream>>>(x, W1, yb);
    {
        unsigned short* y2b = (unsigned short*)(bsum + SCAN_BLOCKS + 32);
        k_gather_h1_mm2<<<aggBlocks, 256, 0, stream>>>(off, srcS, yb, b1, W2, y2b);
        k_gather_tail<<<aggBlocks, 256, 0, stream>>>(off, srcS, y2b, b2, W3, b3,
                                                     W4, b4, out);
    }
}